// Round 2
// baseline (135.611 us; speedup 1.0000x reference)
//
#include <hip/hip_runtime.h>

typedef __attribute__((ext_vector_type(8))) short bf16x8;
typedef __attribute__((ext_vector_type(4))) float f32x4;

__device__ __forceinline__ unsigned short f2bf(float f) {
    unsigned int u = __builtin_bit_cast(unsigned int, f);
    unsigned int r = (u + 0x7FFFu + ((u >> 16) & 1u)) >> 16;
    return (unsigned short)r;
}

__device__ __forceinline__ void gll16(const void* g, void* l) {
    __builtin_amdgcn_global_load_lds(
        (const __attribute__((address_space(1))) void*)g,
        (__attribute__((address_space(3))) void*)l, 16, 0, 0);
}

// ---------------------------------------------------------------------------
// Kernel 0: tiled transpose + fp32->bf16 convert.
// src: [batch][R][C] fp32. dstT: [batch][C][R] bf16. dstS (optional): [batch][R][C] bf16.
// ---------------------------------------------------------------------------
__global__ __launch_bounds__(256) void transpose_cvt_kernel(
    const float* __restrict__ src, unsigned short* __restrict__ dstT,
    unsigned short* __restrict__ dstS, int R, int C)
{
    __shared__ float tile[64][65];
    const int b = blockIdx.z;
    const float* s = src + (size_t)b * R * C;
    const int r0 = blockIdx.x * 64, c0 = blockIdx.y * 64;
    const int t = threadIdx.x;
    const int r = t >> 2, cg = (t & 3) * 16;

    float v[16];
    const float4* p = reinterpret_cast<const float4*>(s + (size_t)(r0 + r) * C + c0 + cg);
#pragma unroll
    for (int i = 0; i < 4; ++i) {
        float4 q = p[i];
        v[4 * i + 0] = q.x; v[4 * i + 1] = q.y; v[4 * i + 2] = q.z; v[4 * i + 3] = q.w;
    }
#pragma unroll
    for (int i = 0; i < 16; ++i) tile[r][cg + i] = v[i];

    if (dstS) {
        unsigned int w[8];
#pragma unroll
        for (int i = 0; i < 8; ++i)
            w[i] = (unsigned)f2bf(v[2 * i]) | ((unsigned)f2bf(v[2 * i + 1]) << 16);
        unsigned int* d = reinterpret_cast<unsigned int*>(
            dstS + (size_t)b * R * C + (size_t)(r0 + r) * C + c0 + cg);
        *reinterpret_cast<uint4*>(d)     = make_uint4(w[0], w[1], w[2], w[3]);
        *reinterpret_cast<uint4*>(d + 4) = make_uint4(w[4], w[5], w[6], w[7]);
    }

    __syncthreads();

    const int cl = t >> 2, rg = (t & 3) * 16;
    unsigned int w[8];
#pragma unroll
    for (int i = 0; i < 8; ++i) {
        unsigned short lo = f2bf(tile[rg + 2 * i][cl]);
        unsigned short hi = f2bf(tile[rg + 2 * i + 1][cl]);
        w[i] = (unsigned)lo | ((unsigned)hi << 16);
    }
    unsigned int* d = reinterpret_cast<unsigned int*>(
        dstT + (size_t)b * R * C + (size_t)(c0 + cl) * R + r0 + rg);
    *reinterpret_cast<uint4*>(d)     = make_uint4(w[0], w[1], w[2], w[3]);
    *reinterpret_cast<uint4*>(d + 4) = make_uint4(w[4], w[5], w[6], w[7]);
}

// ---------------------------------------------------------------------------
// Kernel 1: agg[b] = A[b] (2048x2048 fp32) @ F[b] (2048x256, via F^T bf16)
// BM=128 BN=128 BK=64, 512 threads (8 waves, 2x4 -> wave tile 64x32).
// LDS = 64KB -> 2 blocks/CU resident (grid 512 = 2/CU); launch_bounds(512,4)
// caps VGPR at 128 so residency is real. XCD-swizzled block id: each XCD
// owns 2 whole batches (Ft + A panels stay in its private L2).
// A: reg-staged fp32->bf16 -> swizzled ds_write_b128.
// B (F^T): global_load_lds w=16, pre-swizzled global source, linear LDS dest.
// Swizzle: 16B slot' = slot ^ (row & 7) -> conflict-free b128 reads.
// ---------------------------------------------------------------------------
__global__ __launch_bounds__(512, 4) void k1_agg_gemm(
    const float* __restrict__ A, const unsigned short* __restrict__ Ft,
    unsigned short* __restrict__ agg)
{
    __shared__ short Ab[2][128][64];   // 2 x 16KB
    __shared__ short Bb[2][128][64];   // 2 x 16KB

    const int tid = threadIdx.x;
    const int lane = tid & 63, wid = tid >> 6;
    const int wr = wid >> 2, wc = wid & 3;
    const int lo = lane & 15, hi = lane >> 4;

    // bijective XCD swizzle over 512 blocks (512 % 8 == 0)
    const int bid = blockIdx.x;
    const int wg = ((bid & 7) << 6) | (bid >> 3);
    const int batch = wg >> 5;
    const int mt = (wg & 31) >> 1;
    const int nt = wg & 1;

    const float* Abase = A + ((size_t)batch * 2048 + (size_t)mt * 128) * 2048;
    const unsigned short* Fbase = Ft + (size_t)batch * 256 * 2048 + (size_t)nt * 128 * 2048;

    const int arow = tid >> 2;        // 0..127
    const int acg = tid & 3;          // 16 fp32 each

    f32x4 acc[4][2];
#pragma unroll
    for (int m = 0; m < 4; ++m)
#pragma unroll
        for (int n = 0; n < 2; ++n) acc[m][n] = (f32x4){0.f, 0.f, 0.f, 0.f};

    float va[16];

    auto load_A = [&](int k0) {
        const float4* p = reinterpret_cast<const float4*>(
            Abase + (size_t)arow * 2048 + k0 + acg * 16);
#pragma unroll
        for (int i = 0; i < 4; ++i) {
            float4 q = p[i];
            va[4 * i + 0] = q.x; va[4 * i + 1] = q.y; va[4 * i + 2] = q.z; va[4 * i + 3] = q.w;
        }
    };
    auto write_A = [&](int buf) {
#pragma unroll
        for (int j = 0; j < 2; ++j) {
            unsigned int w[4];
#pragma unroll
            for (int i = 0; i < 4; ++i) {
                int e = j * 8 + i * 2;
                w[i] = (unsigned)f2bf(va[e]) | ((unsigned)f2bf(va[e + 1]) << 16);
            }
            int slin = acg * 2 + j;
            int off = arow * 64 + ((slin ^ (arow & 7)) << 3);   // elements
            *reinterpret_cast<uint4*>(&Ab[buf][0][0] + off) = make_uint4(w[0], w[1], w[2], w[3]);
        }
    };
    auto stage_B = [&](int buf, int k0) {
#pragma unroll
        for (int it = 0; it < 2; ++it) {
            int si = it * 512 + tid;
            int row = si >> 3, slot = si & 7;
            const unsigned short* g = Fbase + (size_t)row * 2048 + k0 + ((slot ^ (row & 7)) << 3);
            short* l = &Bb[buf][0][0] + (size_t)(it * 512 + (wid << 6)) * 8;
            gll16(g, l);
        }
    };

    load_A(0);
    stage_B(0, 0);
    write_A(0);
    __syncthreads();

    for (int t = 0; t < 32; ++t) {
        const int cur = t & 1;
        const int nxt = cur ^ 1;
        const bool has_next = (t + 1) < 32;
        if (has_next) {
            load_A((t + 1) * 64);       // issue global loads early
            stage_B(nxt, (t + 1) * 64); // async into other buffer
        }
#pragma unroll
        for (int kk = 0; kk < 2; ++kk) {
            bf16x8 af[4], bfv[2];
#pragma unroll
            for (int m = 0; m < 4; ++m) {
                int row = wr * 64 + m * 16 + lo;
                int off = row * 64 + (((kk * 4 + hi) ^ (row & 7)) << 3);
                af[m] = *reinterpret_cast<const bf16x8*>(&Ab[cur][0][0] + off);
            }
#pragma unroll
            for (int n = 0; n < 2; ++n) {
                int row = wc * 32 + n * 16 + lo;
                int off = row * 64 + (((kk * 4 + hi) ^ (row & 7)) << 3);
                bfv[n] = *reinterpret_cast<const bf16x8*>(&Bb[cur][0][0] + off);
            }
#pragma unroll
            for (int m = 0; m < 4; ++m)
#pragma unroll
                for (int n = 0; n < 2; ++n)
                    acc[m][n] = __builtin_amdgcn_mfma_f32_16x16x32_bf16(af[m], bfv[n], acc[m][n], 0, 0, 0);
        }
        if (has_next) write_A(nxt);
        __syncthreads();
    }

    unsigned short* obase = agg + ((size_t)batch * 2048 + (size_t)mt * 128) * 256 + nt * 128;
#pragma unroll
    for (int m = 0; m < 4; ++m) {
#pragma unroll
        for (int n = 0; n < 2; ++n) {
            int col = wc * 32 + n * 16 + lo;
#pragma unroll
            for (int j = 0; j < 4; ++j) {
                int row = wr * 64 + m * 16 + hi * 4 + j;
                obase[(size_t)row * 256 + col] = f2bf(acc[m][n][j]);
            }
        }
    }
}

// ---------------------------------------------------------------------------
// Kernel 2: out[m][f] = relu( X[m] @ W + bias ), X = [F_bf16 | agg] (K=512),
// M=32768 rows, N=256. BM=128 BN=128 BK=64 -> 64KB LDS, grid 512 = 2/CU.
// ---------------------------------------------------------------------------
__global__ __launch_bounds__(512, 4) void k2_out_gemm(
    const unsigned short* __restrict__ Fb, const unsigned short* __restrict__ aggp,
    const unsigned short* __restrict__ Wt, const float* __restrict__ bias,
    float* __restrict__ out)
{
    __shared__ short Ab[2][128][64];
    __shared__ short Bb[2][128][64];

    const int tid = threadIdx.x;
    const int lane = tid & 63, wid = tid >> 6;
    const int wr = wid >> 2, wc = wid & 3;
    const int lo = lane & 15, hi = lane >> 4;
    const int m0 = (blockIdx.x >> 1) * 128;
    const int f0 = (blockIdx.x & 1) * 128;

    auto stage_A = [&](int buf, int k0) {
        const unsigned short* src = (k0 < 256) ? Fb : aggp;
        const int kk0 = k0 & 255;
#pragma unroll
        for (int it = 0; it < 2; ++it) {
            int si = it * 512 + tid;
            int row = si >> 3, slot = si & 7;
            const unsigned short* g = src + (size_t)(m0 + row) * 256 + kk0 + ((slot ^ (row & 7)) << 3);
            short* l = &Ab[buf][0][0] + (size_t)(it * 512 + (wid << 6)) * 8;
            gll16(g, l);
        }
    };
    auto stage_B = [&](int buf, int k0) {
#pragma unroll
        for (int it = 0; it < 2; ++it) {
            int si = it * 512 + tid;
            int row = si >> 3, slot = si & 7;
            const unsigned short* g = Wt + (size_t)(f0 + row) * 512 + k0 + ((slot ^ (row & 7)) << 3);
            short* l = &Bb[buf][0][0] + (size_t)(it * 512 + (wid << 6)) * 8;
            gll16(g, l);
        }
    };

    f32x4 acc[4][2];
#pragma unroll
    for (int m = 0; m < 4; ++m)
#pragma unroll
        for (int n = 0; n < 2; ++n) acc[m][n] = (f32x4){0.f, 0.f, 0.f, 0.f};

    stage_A(0, 0);
    stage_B(0, 0);
    __syncthreads();

    for (int t = 0; t < 8; ++t) {
        const int cur = t & 1;
        const int nxt = cur ^ 1;
        const bool has_next = (t + 1) < 8;
        if (has_next) {
            stage_A(nxt, (t + 1) * 64);
            stage_B(nxt, (t + 1) * 64);
        }
#pragma unroll
        for (int kk = 0; kk < 2; ++kk) {
            bf16x8 af[4], bfv[2];
#pragma unroll
            for (int m = 0; m < 4; ++m) {
                int row = wr * 64 + m * 16 + lo;
                int off = row * 64 + (((kk * 4 + hi) ^ (row & 7)) << 3);
                af[m] = *reinterpret_cast<const bf16x8*>(&Ab[cur][0][0] + off);
            }
#pragma unroll
            for (int n = 0; n < 2; ++n) {
                int row = wc * 32 + n * 16 + lo;
                int off = row * 64 + (((kk * 4 + hi) ^ (row & 7)) << 3);
                bfv[n] = *reinterpret_cast<const bf16x8*>(&Bb[cur][0][0] + off);
            }
#pragma unroll
            for (int m = 0; m < 4; ++m)
#pragma unroll
                for (int n = 0; n < 2; ++n)
                    acc[m][n] = __builtin_amdgcn_mfma_f32_16x16x32_bf16(af[m], bfv[n], acc[m][n], 0, 0, 0);
        }
        __syncthreads();
    }

    float bv[2];
#pragma unroll
    for (int n = 0; n < 2; ++n) bv[n] = bias[f0 + wc * 32 + n * 16 + lo];

#pragma unroll
    for (int m = 0; m < 4; ++m) {
#pragma unroll
        for (int n = 0; n < 2; ++n) {
            int col = f0 + wc * 32 + n * 16 + lo;
#pragma unroll
            for (int j = 0; j < 4; ++j) {
                int row = m0 + wr * 64 + m * 16 + hi * 4 + j;
                float v = acc[m][n][j] + bv[n];
                out[(size_t)row * 256 + col] = fmaxf(v, 0.f);
            }
        }
    }
}

// ---------------------------------------------------------------------------
extern "C" void kernel_launch(void* const* d_in, const int* in_sizes, int n_in,
                              void* d_out, int out_size, void* d_ws, size_t ws_size,
                              hipStream_t stream) {
    const float* features = (const float*)d_in[0];   // [16][2048][256]
    const float* A        = (const float*)d_in[1];   // [16][2048][2048]
    const float* weight   = (const float*)d_in[2];   // [512][256]
    const float* bias     = (const float*)d_in[3];   // [256]
    float* out = (float*)d_out;

    const size_t F_ELEMS = (size_t)16 * 2048 * 256;          // 8388608
    const size_t FT_B  = F_ELEMS * 2;                        // 16 MB
    const size_t FB_B  = F_ELEMS * 2;
    const size_t WT_B  = (size_t)256 * 512 * 2;              // 256 KB
    const size_t AGG_B = F_ELEMS * 2;
    if (ws_size < FT_B + FB_B + WT_B + AGG_B) return;

    char* ws = (char*)d_ws;
    unsigned short* Ft  = (unsigned short*)ws;
    unsigned short* Fb  = (unsigned short*)(ws + FT_B);
    unsigned short* Wt  = (unsigned short*)(ws + FT_B + FB_B);
    unsigned short* agg = (unsigned short*)(ws + FT_B + FB_B + WT_B);

    dim3 gF(2048 / 64, 256 / 64, 16);
    transpose_cvt_kernel<<<gF, 256, 0, stream>>>(features, Ft, Fb, 2048, 256);
    dim3 gW(512 / 64, 256 / 64, 1);
    transpose_cvt_kernel<<<gW, 256, 0, stream>>>(weight, Wt, nullptr, 512, 256);

    k1_agg_gemm<<<512, 512, 0, stream>>>(A, Ft, agg);

    k2_out_gemm<<<512, 512, 0, stream>>>(Fb, agg, Wt, bias, out);
}

// Round 3
// 126.368 us; speedup vs baseline: 1.0731x; 1.0731x over previous
//
#include <hip/hip_runtime.h>

typedef __attribute__((ext_vector_type(8))) short bf16x8;
typedef __attribute__((ext_vector_type(4))) float f32x4;

// RNE bf16 (epilogues / transpose — off critical path)
__device__ __forceinline__ unsigned short f2bf(float f) {
    unsigned int u = __builtin_bit_cast(unsigned int, f);
    unsigned int r = (u + 0x7FFFu + ((u >> 16) & 1u)) >> 16;
    return (unsigned short)r;
}
// round-half-up pack of two fp32 -> packed bf16x2 (5 VALU) — k1 A staging hot path
__device__ __forceinline__ unsigned int pkbf(float lo, float hi) {
    unsigned int ul = __builtin_bit_cast(unsigned int, lo) + 0x8000u;
    unsigned int uh = __builtin_bit_cast(unsigned int, hi) + 0x8000u;
    return (uh & 0xFFFF0000u) | (ul >> 16);
}

__device__ __forceinline__ void gll16(const void* g, void* l) {
    __builtin_amdgcn_global_load_lds(
        (const __attribute__((address_space(1))) void*)g,
        (__attribute__((address_space(3))) void*)l, 16, 0, 0);
}

// ---------------------------------------------------------------------------
// Kernel 0: tiled transpose + fp32->bf16. src [b][R][C] f32 -> dstT [b][C][R] bf16,
// optional dstS [b][R][C] bf16 passthrough.
// ---------------------------------------------------------------------------
__global__ __launch_bounds__(256) void transpose_cvt_kernel(
    const float* __restrict__ src, unsigned short* __restrict__ dstT,
    unsigned short* __restrict__ dstS, int R, int C)
{
    __shared__ float tile[64][65];
    const int b = blockIdx.z;
    const float* s = src + (size_t)b * R * C;
    const int r0 = blockIdx.x * 64, c0 = blockIdx.y * 64;
    const int t = threadIdx.x;
    const int r = t >> 2, cg = (t & 3) * 16;

    float v[16];
    const float4* p = reinterpret_cast<const float4*>(s + (size_t)(r0 + r) * C + c0 + cg);
#pragma unroll
    for (int i = 0; i < 4; ++i) {
        float4 q = p[i];
        v[4 * i + 0] = q.x; v[4 * i + 1] = q.y; v[4 * i + 2] = q.z; v[4 * i + 3] = q.w;
    }
#pragma unroll
    for (int i = 0; i < 16; ++i) tile[r][cg + i] = v[i];

    if (dstS) {
        unsigned int w[8];
#pragma unroll
        for (int i = 0; i < 8; ++i)
            w[i] = (unsigned)f2bf(v[2 * i]) | ((unsigned)f2bf(v[2 * i + 1]) << 16);
        unsigned int* d = reinterpret_cast<unsigned int*>(
            dstS + (size_t)b * R * C + (size_t)(r0 + r) * C + c0 + cg);
        *reinterpret_cast<uint4*>(d)     = make_uint4(w[0], w[1], w[2], w[3]);
        *reinterpret_cast<uint4*>(d + 4) = make_uint4(w[4], w[5], w[6], w[7]);
    }

    __syncthreads();

    const int cl = t >> 2, rg = (t & 3) * 16;
    unsigned int w[8];
#pragma unroll
    for (int i = 0; i < 8; ++i) {
        unsigned short lo = f2bf(tile[rg + 2 * i][cl]);
        unsigned short hi = f2bf(tile[rg + 2 * i + 1][cl]);
        w[i] = (unsigned)lo | ((unsigned)hi << 16);
    }
    unsigned int* d = reinterpret_cast<unsigned int*>(
        dstT + (size_t)b * R * C + (size_t)(c0 + cl) * R + r0 + rg);
    *reinterpret_cast<uint4*>(d)     = make_uint4(w[0], w[1], w[2], w[3]);
    *reinterpret_cast<uint4*>(d + 4) = make_uint4(w[4], w[5], w[6], w[7]);
}

// ---------------------------------------------------------------------------
// Kernel 1: split-K GEMM1. agg_ks[b] = A[b][:, ks*1024:+1024] @ F[ks half]
// BM=128 BN=256 BK=64, K=1024 per split. 512 thr (8 waves 2x4, wave tile 64x64).
// SINGLE-buffered LDS 48KB (m97 shape) -> 2 blocks/CU (grid 512, split-K -> A
// fetch stays 268 MB total, disjoint). 2-barrier K-loop; A reg-staged fp32 ->
// round-half-up bf16 pack -> swizzled ds_write; B via gll w=16 pre-swizzled.
// XCD swizzle: each XCD owns 2 whole batches (Ft L2-local).
// ---------------------------------------------------------------------------
__global__ __launch_bounds__(512, 4) void k1_agg_gemm(
    const float* __restrict__ A, const unsigned short* __restrict__ Ft,
    unsigned short* __restrict__ agg0, unsigned short* __restrict__ agg1)
{
    __shared__ short Ab[128][64];   // 16KB
    __shared__ short Bb[256][64];   // 32KB

    const int tid = threadIdx.x;
    const int lane = tid & 63, wid = tid >> 6;
    const int wr = wid >> 2, wc = wid & 3;
    const int lo = lane & 15, hi = lane >> 4;

    const int bid = blockIdx.x;
    const int wg = ((bid & 7) << 6) | (bid >> 3);   // bijective, 512 % 8 == 0
    const int batch = wg >> 5;
    const int ks    = (wg >> 4) & 1;
    const int mt    = wg & 15;

    const float* Abase = A + ((size_t)batch * 2048 + (size_t)mt * 128) * 2048 + (size_t)ks * 1024;
    const unsigned short* Fbase = Ft + (size_t)batch * 256 * 2048 + (size_t)ks * 1024;

    const int arow = tid >> 2;    // 0..127
    const int acg  = tid & 3;     // 16-float group along k

    f32x4 acc[4][4];
#pragma unroll
    for (int m = 0; m < 4; ++m)
#pragma unroll
        for (int n = 0; n < 4; ++n) acc[m][n] = (f32x4){0.f, 0.f, 0.f, 0.f};

    for (int t = 0; t < 16; ++t) {
        const int k0 = t * 64;
        // A fp32 loads FIRST (pack below then only needs these; gll stays in flight)
        const float4* p = reinterpret_cast<const float4*>(
            Abase + (size_t)arow * 2048 + k0 + acg * 16);
        float4 q0 = p[0], q1 = p[1], q2 = p[2], q3 = p[3];
        // B stage via global_load_lds (async, drains at the barrier)
#pragma unroll
        for (int it = 0; it < 4; ++it) {
            int si = it * 512 + tid;
            int row = si >> 3, slot = si & 7;
            const unsigned short* g = Fbase + (size_t)row * 2048 + k0 + ((slot ^ (row & 7)) << 3);
            short* l = &Bb[0][0] + (size_t)(it * 512 + (wid << 6)) * 8;
            gll16(g, l);
        }
        // pack + swizzled ds_write of the A tile
        unsigned int w0 = pkbf(q0.x, q0.y), w1 = pkbf(q0.z, q0.w);
        unsigned int w2 = pkbf(q1.x, q1.y), w3 = pkbf(q1.z, q1.w);
        unsigned int w4 = pkbf(q2.x, q2.y), w5 = pkbf(q2.z, q2.w);
        unsigned int w6 = pkbf(q3.x, q3.y), w7 = pkbf(q3.z, q3.w);
        {
            int slin = acg * 2;
            int off0 = arow * 64 + (((slin    ) ^ (arow & 7)) << 3);
            int off1 = arow * 64 + (((slin + 1) ^ (arow & 7)) << 3);
            *reinterpret_cast<uint4*>(&Ab[0][0] + off0) = make_uint4(w0, w1, w2, w3);
            *reinterpret_cast<uint4*>(&Ab[0][0] + off1) = make_uint4(w4, w5, w6, w7);
        }
        __syncthreads();   // gll (vmcnt) + ds_write (lgkm) drained

#pragma unroll
        for (int kk = 0; kk < 2; ++kk) {
            bf16x8 af[4], bfv[4];
#pragma unroll
            for (int m = 0; m < 4; ++m) {
                int row = wr * 64 + m * 16 + lo;
                int off = row * 64 + (((kk * 4 + hi) ^ (row & 7)) << 3);
                af[m] = *reinterpret_cast<const bf16x8*>(&Ab[0][0] + off);
            }
#pragma unroll
            for (int n = 0; n < 4; ++n) {
                int row = wc * 64 + n * 16 + lo;
                int off = row * 64 + (((kk * 4 + hi) ^ (row & 7)) << 3);
                bfv[n] = *reinterpret_cast<const bf16x8*>(&Bb[0][0] + off);
            }
#pragma unroll
            for (int m = 0; m < 4; ++m)
#pragma unroll
                for (int n = 0; n < 4; ++n)
                    acc[m][n] = __builtin_amdgcn_mfma_f32_16x16x32_bf16(af[m], bfv[n], acc[m][n], 0, 0, 0);
        }
        __syncthreads();   // all reads done before next overwrite
    }

    unsigned short* obase = (ks ? agg1 : agg0)
        + ((size_t)batch * 2048 + (size_t)mt * 128) * 256;
#pragma unroll
    for (int m = 0; m < 4; ++m) {
#pragma unroll
        for (int n = 0; n < 4; ++n) {
            int col = wc * 64 + n * 16 + lo;
#pragma unroll
            for (int j = 0; j < 4; ++j) {
                int row = wr * 64 + m * 16 + hi * 4 + j;
                obase[(size_t)row * 256 + col] = f2bf(acc[m][n][j]);
            }
        }
    }
}

// ---------------------------------------------------------------------------
// Kernel 2: out = relu([F | agg0 | agg1] @ [W1;W2;W2] + bias). K=768 concat
// trick absorbs the split-K reduction (agg0@W2 + agg1@W2). M=32768, N=256.
// BM=64 BN=256 BK=64, 256 thr (4 waves 1x4), single-buffer 40KB -> grid 512,
// 2 blocks/CU. B-side k-remap reads the same Wt[256][512] (no duplication).
// ---------------------------------------------------------------------------
__global__ __launch_bounds__(256, 2) void k2_out_gemm(
    const unsigned short* __restrict__ Fb, const unsigned short* __restrict__ agg0,
    const unsigned short* __restrict__ agg1, const unsigned short* __restrict__ Wt,
    const float* __restrict__ bias, float* __restrict__ out)
{
    __shared__ short Ab[64][64];    // 8KB
    __shared__ short Bb[256][64];   // 32KB

    const int tid = threadIdx.x;
    const int lane = tid & 63, wid = tid >> 6;   // 4 waves, 1x4
    const int wc = wid;
    const int lo = lane & 15, hi = lane >> 4;
    const int m0 = blockIdx.x * 64;

    f32x4 acc[4][4];
#pragma unroll
    for (int m = 0; m < 4; ++m)
#pragma unroll
        for (int n = 0; n < 4; ++n) acc[m][n] = (f32x4){0.f, 0.f, 0.f, 0.f};

    for (int t = 0; t < 12; ++t) {
        const int k0 = t * 64;
        const unsigned short* asrc = (k0 < 256) ? Fb : (k0 < 512 ? agg0 : agg1);
        const int ak = k0 & 255;
#pragma unroll
        for (int it = 0; it < 2; ++it) {
            int si = it * 256 + tid;
            int row = si >> 3, slot = si & 7;
            const unsigned short* g = asrc + (size_t)(m0 + row) * 256 + ak + ((slot ^ (row & 7)) << 3);
            short* l = &Ab[0][0] + (size_t)(it * 256 + (wid << 6)) * 8;
            gll16(g, l);
        }
        const int bk = (k0 < 512) ? k0 : k0 - 256;   // W2 reused for k in [512,768)
#pragma unroll
        for (int it = 0; it < 8; ++it) {
            int si = it * 256 + tid;
            int row = si >> 3, slot = si & 7;
            const unsigned short* g = Wt + (size_t)row * 512 + bk + ((slot ^ (row & 7)) << 3);
            short* l = &Bb[0][0] + (size_t)(it * 256 + (wid << 6)) * 8;
            gll16(g, l);
        }
        __syncthreads();

#pragma unroll
        for (int kk = 0; kk < 2; ++kk) {
            bf16x8 af[4], bfv[4];
#pragma unroll
            for (int m = 0; m < 4; ++m) {
                int row = m * 16 + lo;
                int off = row * 64 + (((kk * 4 + hi) ^ (row & 7)) << 3);
                af[m] = *reinterpret_cast<const bf16x8*>(&Ab[0][0] + off);
            }
#pragma unroll
            for (int n = 0; n < 4; ++n) {
                int row = wc * 64 + n * 16 + lo;
                int off = row * 64 + (((kk * 4 + hi) ^ (row & 7)) << 3);
                bfv[n] = *reinterpret_cast<const bf16x8*>(&Bb[0][0] + off);
            }
#pragma unroll
            for (int m = 0; m < 4; ++m)
#pragma unroll
                for (int n = 0; n < 4; ++n)
                    acc[m][n] = __builtin_amdgcn_mfma_f32_16x16x32_bf16(af[m], bfv[n], acc[m][n], 0, 0, 0);
        }
        __syncthreads();
    }

    float bv[4];
#pragma unroll
    for (int n = 0; n < 4; ++n) bv[n] = bias[wc * 64 + n * 16 + lo];

#pragma unroll
    for (int m = 0; m < 4; ++m) {
#pragma unroll
        for (int n = 0; n < 4; ++n) {
            int col = wc * 64 + n * 16 + lo;
#pragma unroll
            for (int j = 0; j < 4; ++j) {
                int row = m0 + m * 16 + hi * 4 + j;
                float v = acc[m][n][j] + bv[n];
                out[(size_t)row * 256 + col] = fmaxf(v, 0.f);
            }
        }
    }
}

// ---------------------------------------------------------------------------
extern "C" void kernel_launch(void* const* d_in, const int* in_sizes, int n_in,
                              void* d_out, int out_size, void* d_ws, size_t ws_size,
                              hipStream_t stream) {
    const float* features = (const float*)d_in[0];   // [16][2048][256]
    const float* A        = (const float*)d_in[1];   // [16][2048][2048]
    const float* weight   = (const float*)d_in[2];   // [512][256]
    const float* bias     = (const float*)d_in[3];   // [256]
    float* out = (float*)d_out;

    const size_t F_ELEMS = (size_t)16 * 2048 * 256;
    const size_t FT_B   = F_ELEMS * 2;               // 16.8 MB
    const size_t FB_B   = F_ELEMS * 2;
    const size_t WT_B   = (size_t)256 * 512 * 2;     // 256 KB
    const size_t AGG_B  = F_ELEMS * 2;               // per split half
    if (ws_size < FT_B + FB_B + WT_B + 2 * AGG_B) return;

    char* ws = (char*)d_ws;
    unsigned short* Ft   = (unsigned short*)ws;
    unsigned short* Fb   = (unsigned short*)(ws + FT_B);
    unsigned short* Wt   = (unsigned short*)(ws + FT_B + FB_B);
    unsigned short* agg0 = (unsigned short*)(ws + FT_B + FB_B + WT_B);
    unsigned short* agg1 = (unsigned short*)(ws + FT_B + FB_B + WT_B + AGG_B);

    dim3 gF(2048 / 64, 256 / 64, 16);
    transpose_cvt_kernel<<<gF, 256, 0, stream>>>(features, Ft, Fb, 2048, 256);
    dim3 gW(512 / 64, 256 / 64, 1);
    transpose_cvt_kernel<<<gW, 256, 0, stream>>>(weight, Wt, nullptr, 512, 256);

    k1_agg_gemm<<<512, 512, 0, stream>>>(A, Ft, agg0, agg1);

    k2_out_gemm<<<512, 256, 0, stream>>>(Fb, agg0, agg1, Wt, bias, out);
}

// Round 4
// 115.374 us; speedup vs baseline: 1.1754x; 1.0953x over previous
//
#include <hip/hip_runtime.h>

typedef __attribute__((ext_vector_type(8))) short bf16x8;
typedef __attribute__((ext_vector_type(4))) float f32x4;

// RNE bf16 (epilogues — off critical path)
__device__ __forceinline__ unsigned short f2bf(float f) {
    unsigned int u = __builtin_bit_cast(unsigned int, f);
    unsigned int r = (u + 0x7FFFu + ((u >> 16) & 1u)) >> 16;
    return (unsigned short)r;
}
// round-half-up pack of two fp32 -> packed bf16x2 (cheap) — staging hot path
__device__ __forceinline__ unsigned int pkbf(float lo, float hi) {
    unsigned int ul = __builtin_bit_cast(unsigned int, lo) + 0x8000u;
    unsigned int uh = __builtin_bit_cast(unsigned int, hi) + 0x8000u;
    return (uh & 0xFFFF0000u) | (ul >> 16);
}
__device__ __forceinline__ float bf2f(unsigned short u) {
    unsigned int x = ((unsigned int)u) << 16;
    return __builtin_bit_cast(float, x);
}

__device__ __forceinline__ void gll16(const void* g, void* l) {
    __builtin_amdgcn_global_load_lds(
        (const __attribute__((address_space(1))) void*)g,
        (__attribute__((address_space(3))) void*)l, 16, 0, 0);
}

// ---------------------------------------------------------------------------
// kW: tiled transpose + fp32->bf16 (W only now). src [b][R][C] f32 ->
// dstT [b][C][R] bf16. (dstS path kept for generality, unused.)
// ---------------------------------------------------------------------------
__global__ __launch_bounds__(256) void transpose_cvt_kernel(
    const float* __restrict__ src, unsigned short* __restrict__ dstT,
    unsigned short* __restrict__ dstS, int R, int C)
{
    __shared__ float tile[64][65];
    const int b = blockIdx.z;
    const float* s = src + (size_t)b * R * C;
    const int r0 = blockIdx.x * 64, c0 = blockIdx.y * 64;
    const int t = threadIdx.x;
    const int r = t >> 2, cg = (t & 3) * 16;

    float v[16];
    const float4* p = reinterpret_cast<const float4*>(s + (size_t)(r0 + r) * C + c0 + cg);
#pragma unroll
    for (int i = 0; i < 4; ++i) {
        float4 q = p[i];
        v[4 * i + 0] = q.x; v[4 * i + 1] = q.y; v[4 * i + 2] = q.z; v[4 * i + 3] = q.w;
    }
#pragma unroll
    for (int i = 0; i < 16; ++i) tile[r][cg + i] = v[i];

    if (dstS) {
        unsigned int w[8];
#pragma unroll
        for (int i = 0; i < 8; ++i)
            w[i] = (unsigned)f2bf(v[2 * i]) | ((unsigned)f2bf(v[2 * i + 1]) << 16);
        unsigned int* d = reinterpret_cast<unsigned int*>(
            dstS + (size_t)b * R * C + (size_t)(r0 + r) * C + c0 + cg);
        *reinterpret_cast<uint4*>(d)     = make_uint4(w[0], w[1], w[2], w[3]);
        *reinterpret_cast<uint4*>(d + 4) = make_uint4(w[4], w[5], w[6], w[7]);
    }

    __syncthreads();

    const int cl = t >> 2, rg = (t & 3) * 16;
    unsigned int w[8];
#pragma unroll
    for (int i = 0; i < 8; ++i) {
        unsigned short lo = f2bf(tile[rg + 2 * i][cl]);
        unsigned short hi = f2bf(tile[rg + 2 * i + 1][cl]);
        w[i] = (unsigned)lo | ((unsigned)hi << 16);
    }
    unsigned int* d = reinterpret_cast<unsigned int*>(
        dstT + (size_t)b * R * C + (size_t)(c0 + cl) * R + r0 + rg);
    *reinterpret_cast<uint4*>(d)     = make_uint4(w[0], w[1], w[2], w[3]);
    *reinterpret_cast<uint4*>(d + 4) = make_uint4(w[4], w[5], w[6], w[7]);
}

// ---------------------------------------------------------------------------
// kPre: per 64 F-rows compute H = F@W1 + bias (bf16, row-major) and
// G^T = (F@W2)^T (bf16, [batch][256 f][2048 m]).
// BM=64, N=256, K=256. 256 thr (4 waves, wave tile 64x64).
// F staged ONCE into LDS [64][256] bf16 (XOR-swizzled 16B slots), two passes
// (W1 then W2) restage Wb [256][64] per K-tile via gll w=16 pre-swizzled.
// G^T epilogue: per-wave 8KB LDS transpose (Wb region, exclusively owned),
// then coalesced 128B global writes. LDS 64KB -> 2 blocks/CU, grid 512.
// ---------------------------------------------------------------------------
__global__ __launch_bounds__(256, 2) void kpre_gemm(
    const float* __restrict__ F, const unsigned short* __restrict__ Wt,
    const float* __restrict__ bias, unsigned short* __restrict__ H,
    unsigned short* __restrict__ Gt)
{
    __shared__ __align__(16) short Fb[64 * 256];   // 32KB
    __shared__ __align__(16) short Wb[256 * 64];   // 32KB (+ G^T scratch)

    const int tid = threadIdx.x;
    const int lane = tid & 63, wid = tid >> 6;   // 4 waves
    const int lo = lane & 15, hi = lane >> 4;
    const int rb = blockIdx.x;                   // 0..511
    const int batch = rb >> 5;
    const int mb = (rb & 31) * 64;               // m within batch
    const size_t m0g = (size_t)rb * 64;          // global row

    // ---- stage F tile [64][256] fp32 -> bf16, swizzled ----
    {
        const int frow = tid >> 2, fq = tid & 3;
        const float* fp = F + (m0g + frow) * 256 + fq * 64;
#pragma unroll
        for (int g = 0; g < 2; ++g) {
            float4 q[8];
#pragma unroll
            for (int i = 0; i < 8; ++i)
                q[i] = reinterpret_cast<const float4*>(fp)[g * 8 + i];
#pragma unroll
            for (int j = 0; j < 4; ++j) {
                unsigned int w0 = pkbf(q[2*j].x,   q[2*j].y);
                unsigned int w1 = pkbf(q[2*j].z,   q[2*j].w);
                unsigned int w2 = pkbf(q[2*j+1].x, q[2*j+1].y);
                unsigned int w3 = pkbf(q[2*j+1].z, q[2*j+1].w);
                int slot = fq * 8 + g * 4 + j;
                int off = frow * 256 + ((slot ^ (frow & 7)) << 3);
                *reinterpret_cast<uint4*>(&Fb[off]) = make_uint4(w0, w1, w2, w3);
            }
        }
    }
    // first __syncthreads below covers Fb (lgkm) + first Wb stage (vmcnt)

    f32x4 acc[4][4];

#pragma unroll
    for (int pass = 0; pass < 2; ++pass) {
#pragma unroll
        for (int m = 0; m < 4; ++m)
#pragma unroll
            for (int n = 0; n < 4; ++n) acc[m][n] = (f32x4){0.f, 0.f, 0.f, 0.f};

        for (int kt = 0; kt < 4; ++kt) {
            const int kbase = pass * 256 + kt * 64;
#pragma unroll
            for (int it = 0; it < 8; ++it) {
                int si = it * 256 + tid;
                int row = si >> 3, slot = si & 7;
                const unsigned short* g = Wt + (size_t)row * 512 + kbase + ((slot ^ (row & 7)) << 3);
                gll16(g, Wb + (size_t)si * 8);
            }
            __syncthreads();

#pragma unroll
            for (int kk = 0; kk < 2; ++kk) {
                bf16x8 af[4], bw[4];
#pragma unroll
                for (int m = 0; m < 4; ++m) {
                    int row = m * 16 + lo;
                    int slot = kt * 8 + kk * 4 + hi;
                    af[m] = *reinterpret_cast<const bf16x8*>(&Fb[row * 256 + ((slot ^ (row & 7)) << 3)]);
                }
#pragma unroll
                for (int n = 0; n < 4; ++n) {
                    int row = wid * 64 + n * 16 + lo;
                    bw[n] = *reinterpret_cast<const bf16x8*>(&Wb[row * 64 + (((kk * 4 + hi) ^ (row & 7)) << 3)]);
                }
#pragma unroll
                for (int m = 0; m < 4; ++m)
#pragma unroll
                    for (int n = 0; n < 4; ++n)
                        acc[m][n] = __builtin_amdgcn_mfma_f32_16x16x32_bf16(af[m], bw[n], acc[m][n], 0, 0, 0);
            }
            __syncthreads();
        }

        if (pass == 0) {
            // H = acc + bias, bf16 row-major [32768][256]
            float bv[4];
#pragma unroll
            for (int n = 0; n < 4; ++n) bv[n] = bias[wid * 64 + n * 16 + lo];
            unsigned short* Hb = H + m0g * 256;
#pragma unroll
            for (int m = 0; m < 4; ++m)
#pragma unroll
                for (int n = 0; n < 4; ++n)
#pragma unroll
                    for (int j = 0; j < 4; ++j) {
                        int row = m * 16 + hi * 4 + j;
                        int col = wid * 64 + n * 16 + lo;
                        Hb[(size_t)row * 256 + col] = f2bf(acc[m][n][j] + bv[n]);
                    }
        } else {
            // G^T: transpose 64x64 wave tile through own Wb region (8KB)
            short* T = Wb + wid * 4096;
#pragma unroll
            for (int m = 0; m < 4; ++m)
#pragma unroll
                for (int n = 0; n < 4; ++n)
#pragma unroll
                    for (int j = 0; j < 4; ++j) {
                        int gr = m * 16 + hi * 4 + j;   // m-local
                        int gc = n * 16 + lo;           // f-local
                        int slot = gr >> 3, e = gr & 7;
                        T[gc * 64 + ((slot ^ (gc & 7)) << 3) + e] = f2bf(acc[m][n][j]);
                    }
            // wave-local region: lockstep within wave; compiler orders lgkm
            unsigned short* Gb = Gt + ((size_t)batch * 256 + wid * 64) * 2048 + mb;
#pragma unroll
            for (int i = 0; i < 8; ++i) {
                int f = i * 8 + (lane >> 3);
                int s = lane & 7;
                bf16x8 v = *reinterpret_cast<const bf16x8*>(&T[f * 64 + ((s ^ (f & 7)) << 3)]);
                *reinterpret_cast<bf16x8*>(Gb + (size_t)f * 2048 + s * 8) = v;
            }
        }
    }
}

// ---------------------------------------------------------------------------
// kMain: out = relu(H + A @ G) per batch. A [2048][2048] fp32, G via
// G^T bf16 [256][2048]. BM=128 BN=256 BK=64, 512 thr (8 waves 2x4,
// wave tile 64x64). Single-buffered 48KB LDS, 2-barrier loop, reg-level
// A-prefetch (t+1 fp32 loads overlap compute t). grid 256 (16b x 16mt),
// XCD-swizzled: each XCD owns 2 batches (G^T stays L2-local).
// ---------------------------------------------------------------------------
__global__ __launch_bounds__(512, 2) void kmain_gemm(
    const float* __restrict__ A, const unsigned short* __restrict__ Gt,
    const unsigned short* __restrict__ H, float* __restrict__ out)
{
    __shared__ __align__(16) short Ab[128 * 64];   // 16KB
    __shared__ __align__(16) short Bb[256 * 64];   // 32KB

    const int tid = threadIdx.x;
    const int lane = tid & 63, wid = tid >> 6;
    const int wr = wid >> 2, wc = wid & 3;
    const int lo = lane & 15, hi = lane >> 4;

    const int bid = blockIdx.x;
    const int wg = ((bid & 7) << 5) | (bid >> 3);   // bijective, 256 % 8 == 0
    const int batch = wg >> 4;
    const int mt    = wg & 15;

    const float* Abase = A + ((size_t)batch * 2048 + (size_t)mt * 128) * 2048;
    const unsigned short* Gbase = Gt + (size_t)batch * 256 * 2048;

    const int arow = tid >> 2;    // 0..127
    const int acg  = tid & 3;     // 16-float group along k

    f32x4 acc[4][4];
#pragma unroll
    for (int m = 0; m < 4; ++m)
#pragma unroll
        for (int n = 0; n < 4; ++n) acc[m][n] = (f32x4){0.f, 0.f, 0.f, 0.f};

    float4 qa[4];
    auto load_A = [&](int k0) {
        const float4* p = reinterpret_cast<const float4*>(
            Abase + (size_t)arow * 2048 + k0 + acg * 16);
#pragma unroll
        for (int i = 0; i < 4; ++i) qa[i] = p[i];
    };

    load_A(0);

    for (int t = 0; t < 32; ++t) {
        const int k0 = t * 64;
        // B stage via global_load_lds (async; drains at barrier)
#pragma unroll
        for (int it = 0; it < 4; ++it) {
            int si = it * 512 + tid;
            int row = si >> 3, slot = si & 7;
            const unsigned short* g = Gbase + (size_t)row * 2048 + k0 + ((slot ^ (row & 7)) << 3);
            gll16(g, Bb + (size_t)si * 8);
        }
        // pack current A regs -> swizzled ds_write
        {
            unsigned int w0 = pkbf(qa[0].x, qa[0].y), w1 = pkbf(qa[0].z, qa[0].w);
            unsigned int w2 = pkbf(qa[1].x, qa[1].y), w3 = pkbf(qa[1].z, qa[1].w);
            unsigned int w4 = pkbf(qa[2].x, qa[2].y), w5 = pkbf(qa[2].z, qa[2].w);
            unsigned int w6 = pkbf(qa[3].x, qa[3].y), w7 = pkbf(qa[3].z, qa[3].w);
            int slin = acg * 2;
            int off0 = arow * 64 + (((slin    ) ^ (arow & 7)) << 3);
            int off1 = arow * 64 + (((slin + 1) ^ (arow & 7)) << 3);
            *reinterpret_cast<uint4*>(&Ab[off0]) = make_uint4(w0, w1, w2, w3);
            *reinterpret_cast<uint4*>(&Ab[off1]) = make_uint4(w4, w5, w6, w7);
        }
        __syncthreads();   // gll (vmcnt) + ds_write (lgkm) drained

        if (t + 1 < 32) load_A((t + 1) * 64);   // prefetch next A into regs (overlaps MFMA)

#pragma unroll
        for (int kk = 0; kk < 2; ++kk) {
            bf16x8 af[4], bfv[4];
#pragma unroll
            for (int m = 0; m < 4; ++m) {
                int row = wr * 64 + m * 16 + lo;
                af[m] = *reinterpret_cast<const bf16x8*>(&Ab[row * 64 + (((kk * 4 + hi) ^ (row & 7)) << 3)]);
            }
#pragma unroll
            for (int n = 0; n < 4; ++n) {
                int row = wc * 64 + n * 16 + lo;
                bfv[n] = *reinterpret_cast<const bf16x8*>(&Bb[row * 64 + (((kk * 4 + hi) ^ (row & 7)) << 3)]);
            }
#pragma unroll
            for (int m = 0; m < 4; ++m)
#pragma unroll
                for (int n = 0; n < 4; ++n)
                    acc[m][n] = __builtin_amdgcn_mfma_f32_16x16x32_bf16(af[m], bfv[n], acc[m][n], 0, 0, 0);
        }
        __syncthreads();   // all LDS reads done before next overwrite
    }

    // epilogue: out = relu(acc + H)
    const size_t rowbase = (size_t)batch * 2048 + (size_t)mt * 128;
    const unsigned short* Hb = H + rowbase * 256;
    float* obase = out + rowbase * 256;
#pragma unroll
    for (int m = 0; m < 4; ++m) {
#pragma unroll
        for (int n = 0; n < 4; ++n) {
            int col = wc * 64 + n * 16 + lo;
#pragma unroll
            for (int j = 0; j < 4; ++j) {
                int row = wr * 64 + m * 16 + hi * 4 + j;
                float v = acc[m][n][j] + bf2f(Hb[(size_t)row * 256 + col]);
                obase[(size_t)row * 256 + col] = fmaxf(v, 0.f);
            }
        }
    }
}

// ---------------------------------------------------------------------------
extern "C" void kernel_launch(void* const* d_in, const int* in_sizes, int n_in,
                              void* d_out, int out_size, void* d_ws, size_t ws_size,
                              hipStream_t stream) {
    const float* features = (const float*)d_in[0];   // [16][2048][256]
    const float* A        = (const float*)d_in[1];   // [16][2048][2048]
    const float* weight   = (const float*)d_in[2];   // [512][256]
    const float* bias     = (const float*)d_in[3];   // [256]
    float* out = (float*)d_out;

    const size_t WT_B = (size_t)256 * 512 * 2;             // 256 KB
    const size_t H_B  = (size_t)32768 * 256 * 2;           // 16.78 MB
    const size_t GT_B = (size_t)16 * 256 * 2048 * 2;       // 16.78 MB
    if (ws_size < WT_B + H_B + GT_B) return;

    char* ws = (char*)d_ws;
    unsigned short* Wt = (unsigned short*)ws;
    unsigned short* H  = (unsigned short*)(ws + WT_B);
    unsigned short* Gt = (unsigned short*)(ws + WT_B + H_B);

    // W [512][256] fp32 -> Wt [256][512] bf16
    dim3 gW(512 / 64, 256 / 64, 1);
    transpose_cvt_kernel<<<gW, 256, 0, stream>>>(weight, Wt, nullptr, 512, 256);

    // H = F@W1 + bias ; G^T = (F@W2)^T
    kpre_gemm<<<512, 256, 0, stream>>>(features, Wt, bias, H, Gt);

    // out = relu(H + A@G)
    kmain_gemm<<<256, 512, 0, stream>>>(A, Gt, H, out);
}

// Round 5
// 112.646 us; speedup vs baseline: 1.2039x; 1.0242x over previous
//
#include <hip/hip_runtime.h>

typedef __attribute__((ext_vector_type(8))) short bf16x8;
typedef __attribute__((ext_vector_type(4))) float f32x4;

// RNE bf16 (epilogues — off critical path)
__device__ __forceinline__ unsigned short f2bf(float f) {
    unsigned int u = __builtin_bit_cast(unsigned int, f);
    unsigned int r = (u + 0x7FFFu + ((u >> 16) & 1u)) >> 16;
    return (unsigned short)r;
}
// round-half-up pack of two fp32 -> packed bf16x2 (cheap) — staging hot path
__device__ __forceinline__ unsigned int pkbf(float lo, float hi) {
    unsigned int ul = __builtin_bit_cast(unsigned int, lo) + 0x8000u;
    unsigned int uh = __builtin_bit_cast(unsigned int, hi) + 0x8000u;
    return (uh & 0xFFFF0000u) | (ul >> 16);
}
__device__ __forceinline__ float bf2f(unsigned short u) {
    unsigned int x = ((unsigned int)u) << 16;
    return __builtin_bit_cast(float, x);
}

__device__ __forceinline__ void gll16(const void* g, void* l) {
    __builtin_amdgcn_global_load_lds(
        (const __attribute__((address_space(1))) void*)g,
        (__attribute__((address_space(3))) void*)l, 16, 0, 0);
}

// ---------------------------------------------------------------------------
// kW: tiled transpose + fp32->bf16. src [b][R][C] f32 -> dstT [b][C][R] bf16.
// ---------------------------------------------------------------------------
__global__ __launch_bounds__(256) void transpose_cvt_kernel(
    const float* __restrict__ src, unsigned short* __restrict__ dstT,
    unsigned short* __restrict__ dstS, int R, int C)
{
    __shared__ float tile[64][65];
    const int b = blockIdx.z;
    const float* s = src + (size_t)b * R * C;
    const int r0 = blockIdx.x * 64, c0 = blockIdx.y * 64;
    const int t = threadIdx.x;
    const int r = t >> 2, cg = (t & 3) * 16;

    float v[16];
    const float4* p = reinterpret_cast<const float4*>(s + (size_t)(r0 + r) * C + c0 + cg);
#pragma unroll
    for (int i = 0; i < 4; ++i) {
        float4 q = p[i];
        v[4 * i + 0] = q.x; v[4 * i + 1] = q.y; v[4 * i + 2] = q.z; v[4 * i + 3] = q.w;
    }
#pragma unroll
    for (int i = 0; i < 16; ++i) tile[r][cg + i] = v[i];

    if (dstS) {
        unsigned int w[8];
#pragma unroll
        for (int i = 0; i < 8; ++i)
            w[i] = (unsigned)f2bf(v[2 * i]) | ((unsigned)f2bf(v[2 * i + 1]) << 16);
        unsigned int* d = reinterpret_cast<unsigned int*>(
            dstS + (size_t)b * R * C + (size_t)(r0 + r) * C + c0 + cg);
        *reinterpret_cast<uint4*>(d)     = make_uint4(w[0], w[1], w[2], w[3]);
        *reinterpret_cast<uint4*>(d + 4) = make_uint4(w[4], w[5], w[6], w[7]);
    }

    __syncthreads();

    const int cl = t >> 2, rg = (t & 3) * 16;
    unsigned int w[8];
#pragma unroll
    for (int i = 0; i < 8; ++i) {
        unsigned short lo = f2bf(tile[rg + 2 * i][cl]);
        unsigned short hi = f2bf(tile[rg + 2 * i + 1][cl]);
        w[i] = (unsigned)lo | ((unsigned)hi << 16);
    }
    unsigned int* d = reinterpret_cast<unsigned int*>(
        dstT + (size_t)b * R * C + (size_t)(c0 + cl) * R + r0 + rg);
    *reinterpret_cast<uint4*>(d)     = make_uint4(w[0], w[1], w[2], w[3]);
    *reinterpret_cast<uint4*>(d + 4) = make_uint4(w[4], w[5], w[6], w[7]);
}

// ---------------------------------------------------------------------------
// kPre: H = F@W1 + bias (bf16 row-major) and G^T = (F@W2)^T (bf16
// [batch][256][2048]). Unchanged from R4 (passed; ~8 µs).
// ---------------------------------------------------------------------------
__global__ __launch_bounds__(256, 2) void kpre_gemm(
    const float* __restrict__ F, const unsigned short* __restrict__ Wt,
    const float* __restrict__ bias, unsigned short* __restrict__ H,
    unsigned short* __restrict__ Gt)
{
    __shared__ __align__(16) short Fb[64 * 256];   // 32KB
    __shared__ __align__(16) short Wb[256 * 64];   // 32KB (+ G^T scratch)

    const int tid = threadIdx.x;
    const int lane = tid & 63, wid = tid >> 6;   // 4 waves
    const int lo = lane & 15, hi = lane >> 4;
    const int rb = blockIdx.x;                   // 0..511
    const int batch = rb >> 5;
    const int mb = (rb & 31) * 64;
    const size_t m0g = (size_t)rb * 64;

    {
        const int frow = tid >> 2, fq = tid & 3;
        const float* fp = F + (m0g + frow) * 256 + fq * 64;
#pragma unroll
        for (int g = 0; g < 2; ++g) {
            float4 q[8];
#pragma unroll
            for (int i = 0; i < 8; ++i)
                q[i] = reinterpret_cast<const float4*>(fp)[g * 8 + i];
#pragma unroll
            for (int j = 0; j < 4; ++j) {
                unsigned int w0 = pkbf(q[2*j].x,   q[2*j].y);
                unsigned int w1 = pkbf(q[2*j].z,   q[2*j].w);
                unsigned int w2 = pkbf(q[2*j+1].x, q[2*j+1].y);
                unsigned int w3 = pkbf(q[2*j+1].z, q[2*j+1].w);
                int slot = fq * 8 + g * 4 + j;
                int off = frow * 256 + ((slot ^ (frow & 7)) << 3);
                *reinterpret_cast<uint4*>(&Fb[off]) = make_uint4(w0, w1, w2, w3);
            }
        }
    }

    f32x4 acc[4][4];

#pragma unroll
    for (int pass = 0; pass < 2; ++pass) {
#pragma unroll
        for (int m = 0; m < 4; ++m)
#pragma unroll
            for (int n = 0; n < 4; ++n) acc[m][n] = (f32x4){0.f, 0.f, 0.f, 0.f};

        for (int kt = 0; kt < 4; ++kt) {
            const int kbase = pass * 256 + kt * 64;
#pragma unroll
            for (int it = 0; it < 8; ++it) {
                int si = it * 256 + tid;
                int row = si >> 3, slot = si & 7;
                const unsigned short* g = Wt + (size_t)row * 512 + kbase + ((slot ^ (row & 7)) << 3);
                gll16(g, Wb + (size_t)si * 8);
            }
            __syncthreads();

#pragma unroll
            for (int kk = 0; kk < 2; ++kk) {
                bf16x8 af[4], bw[4];
#pragma unroll
                for (int m = 0; m < 4; ++m) {
                    int row = m * 16 + lo;
                    int slot = kt * 8 + kk * 4 + hi;
                    af[m] = *reinterpret_cast<const bf16x8*>(&Fb[row * 256 + ((slot ^ (row & 7)) << 3)]);
                }
#pragma unroll
                for (int n = 0; n < 4; ++n) {
                    int row = wid * 64 + n * 16 + lo;
                    bw[n] = *reinterpret_cast<const bf16x8*>(&Wb[row * 64 + (((kk * 4 + hi) ^ (row & 7)) << 3)]);
                }
#pragma unroll
                for (int m = 0; m < 4; ++m)
#pragma unroll
                    for (int n = 0; n < 4; ++n)
                        acc[m][n] = __builtin_amdgcn_mfma_f32_16x16x32_bf16(af[m], bw[n], acc[m][n], 0, 0, 0);
            }
            __syncthreads();
        }

        if (pass == 0) {
            float bv[4];
#pragma unroll
            for (int n = 0; n < 4; ++n) bv[n] = bias[wid * 64 + n * 16 + lo];
            unsigned short* Hb = H + m0g * 256;
#pragma unroll
            for (int m = 0; m < 4; ++m)
#pragma unroll
                for (int n = 0; n < 4; ++n)
#pragma unroll
                    for (int j = 0; j < 4; ++j) {
                        int row = m * 16 + hi * 4 + j;
                        int col = wid * 64 + n * 16 + lo;
                        Hb[(size_t)row * 256 + col] = f2bf(acc[m][n][j] + bv[n]);
                    }
        } else {
            short* T = Wb + wid * 4096;
#pragma unroll
            for (int m = 0; m < 4; ++m)
#pragma unroll
                for (int n = 0; n < 4; ++n)
#pragma unroll
                    for (int j = 0; j < 4; ++j) {
                        int gr = m * 16 + hi * 4 + j;
                        int gc = n * 16 + lo;
                        int slot = gr >> 3, e = gr & 7;
                        T[gc * 64 + ((slot ^ (gc & 7)) << 3) + e] = f2bf(acc[m][n][j]);
                    }
            unsigned short* Gb = Gt + ((size_t)batch * 256 + wid * 64) * 2048 + mb;
#pragma unroll
            for (int i = 0; i < 8; ++i) {
                int f = i * 8 + (lane >> 3);
                int s = lane & 7;
                bf16x8 v = *reinterpret_cast<const bf16x8*>(&T[f * 64 + ((s ^ (f & 7)) << 3)]);
                *reinterpret_cast<bf16x8*>(Gb + (size_t)f * 2048 + s * 8) = v;
            }
        }
    }
}

// ---------------------------------------------------------------------------
// kMain: out = relu(H + A @ G). Counted-vmcnt double-buffered pipeline (T3+T4
// minimum form): per K-step the barrier waits vmcnt(4) — next-next A-loads
// stay in flight across it; vmcnt(0) never appears in the steady loop.
// BM=128 BN=256 BK=64, 8 waves (2x4, wave tile 64x64), 96KB LDS, 1 block/CU,
// grid 256, XCD-swizzled. A: fp32 reg-prefetch (2 named sets, depth 2) ->
// round-half-up pack -> swizzled ds_write. B (G^T bf16): gll w=16 depth-2.
// ---------------------------------------------------------------------------
__global__ __launch_bounds__(512, 2) void kmain_gemm(
    const float* __restrict__ A, const unsigned short* __restrict__ Gt,
    const unsigned short* __restrict__ H, float* __restrict__ out)
{
    __shared__ __align__(16) short Ab[2][128 * 64];   // 2 x 16KB
    __shared__ __align__(16) short Bb[2][256 * 64];   // 2 x 32KB

    const int tid = threadIdx.x;
    const int lane = tid & 63, wid = tid >> 6;
    const int wr = wid >> 2, wc = wid & 3;
    const int lo = lane & 15, hi = lane >> 4;

    const int bid = blockIdx.x;
    const int wg = ((bid & 7) << 5) | (bid >> 3);   // bijective, 256 % 8 == 0
    const int batch = wg >> 4;
    const int mt    = wg & 15;

    const float* Abase = A + ((size_t)batch * 2048 + (size_t)mt * 128) * 2048;
    const unsigned short* Gbase = Gt + (size_t)batch * 256 * 2048;

    const int arow = tid >> 2;    // 0..127
    const int acg  = tid & 3;     // 16-float group along k

    f32x4 acc[4][4];
#pragma unroll
    for (int m = 0; m < 4; ++m)
#pragma unroll
        for (int n = 0; n < 4; ++n) acc[m][n] = (f32x4){0.f, 0.f, 0.f, 0.f};

    float4 qa0[4], qa1[4];   // two named prefetch sets (rule #20: static indexing)

    auto loadA = [&](float4* q, int k0) {
        const float4* p = reinterpret_cast<const float4*>(
            Abase + (size_t)arow * 2048 + k0 + acg * 16);
#pragma unroll
        for (int i = 0; i < 4; ++i) q[i] = p[i];
    };
    auto writeA = [&](int buf, const float4* q) {
        unsigned int w0 = pkbf(q[0].x, q[0].y), w1 = pkbf(q[0].z, q[0].w);
        unsigned int w2 = pkbf(q[1].x, q[1].y), w3 = pkbf(q[1].z, q[1].w);
        unsigned int w4 = pkbf(q[2].x, q[2].y), w5 = pkbf(q[2].z, q[2].w);
        unsigned int w6 = pkbf(q[3].x, q[3].y), w7 = pkbf(q[3].z, q[3].w);
        int slin = acg * 2;
        int off0 = arow * 64 + (((slin    ) ^ (arow & 7)) << 3);
        int off1 = arow * 64 + (((slin + 1) ^ (arow & 7)) << 3);
        *reinterpret_cast<uint4*>(&Ab[buf][off0]) = make_uint4(w0, w1, w2, w3);
        *reinterpret_cast<uint4*>(&Ab[buf][off1]) = make_uint4(w4, w5, w6, w7);
    };
    auto stageB = [&](int buf, int k0) {
#pragma unroll
        for (int it = 0; it < 4; ++it) {
            int si = it * 512 + tid;
            int row = si >> 3, slot = si & 7;
            const unsigned short* g = Gbase + (size_t)row * 2048 + k0 + ((slot ^ (row & 7)) << 3);
            gll16(g, &Bb[buf][(size_t)si * 8]);
        }
    };
    auto compute = [&](int buf) {
#pragma unroll
        for (int kk = 0; kk < 2; ++kk) {
            bf16x8 af[4], bfv[4];
#pragma unroll
            for (int m = 0; m < 4; ++m) {
                int row = wr * 64 + m * 16 + lo;
                af[m] = *reinterpret_cast<const bf16x8*>(
                    &Ab[buf][row * 64 + (((kk * 4 + hi) ^ (row & 7)) << 3)]);
            }
#pragma unroll
            for (int n = 0; n < 4; ++n) {
                int row = wc * 64 + n * 16 + lo;
                bfv[n] = *reinterpret_cast<const bf16x8*>(
                    &Bb[buf][row * 64 + (((kk * 4 + hi) ^ (row & 7)) << 3)]);
            }
            __builtin_amdgcn_s_setprio(1);
#pragma unroll
            for (int m = 0; m < 4; ++m)
#pragma unroll
                for (int n = 0; n < 4; ++n)
                    acc[m][n] = __builtin_amdgcn_mfma_f32_16x16x32_bf16(af[m], bfv[n], acc[m][n], 0, 0, 0);
            __builtin_amdgcn_s_setprio(0);
        }
    };

    // ---- prologue: fill tile 0+1 pipelines ----
    loadA(qa0, 0);                 // A(0)            [vm: A0 x4]
    stageB(0, 0);                  // B(0) -> Bb[0]   [vm: A0,gll0]
    writeA(0, qa0);                // waits vmcnt(4) -> A0 done; pack -> Ab[0]
    loadA(qa1, 64);                // A(1)            [vm: gll0, A1]
    asm volatile("s_waitcnt vmcnt(4) lgkmcnt(0)" ::: "memory");  // gll0 done
    __builtin_amdgcn_s_barrier();
    asm volatile("" ::: "memory");
    stageB(1, 64);                 // B(1) -> Bb[1]   [vm: A1, gll1]

    // ---- steady: bodies t = 0..29, paired even/odd ----
    for (int tt = 0; tt < 15; ++tt) {
        const int t0 = tt * 2;
        // t even: cur=0
        writeA(1, qa1);                    // A(t+1) -> Ab[1]  (waits vmcnt(4))
        loadA(qa0, (t0 + 2) * 64);         // A(t+2) in flight
        compute(0);
        asm volatile("s_waitcnt vmcnt(4) lgkmcnt(0)" ::: "memory");  // gll(t+1) done, A(t+2) in flight
        __builtin_amdgcn_s_barrier();
        asm volatile("" ::: "memory");
        stageB(0, (t0 + 2) * 64);          // B(t+2) -> Bb[0]
        // t odd: cur=1
        writeA(0, qa0);                    // A(t+2) -> Ab[0]
        loadA(qa1, (t0 + 3) * 64);         // A(t+3)
        compute(1);
        asm volatile("s_waitcnt vmcnt(4) lgkmcnt(0)" ::: "memory");
        __builtin_amdgcn_s_barrier();
        asm volatile("" ::: "memory");
        stageB(1, (t0 + 3) * 64);          // B(t+3) -> Bb[1]
    }
    // ---- tail: t=30 (cur=0), t=31 (cur=1) ----
    writeA(1, qa1);                        // A(31) -> Ab[1]
    compute(0);
    asm volatile("s_waitcnt vmcnt(0) lgkmcnt(0)" ::: "memory");   // drain gll(31)
    __builtin_amdgcn_s_barrier();
    asm volatile("" ::: "memory");
    compute(1);

    // ---- epilogue: out = relu(acc + H) ----
    const size_t rowbase = (size_t)batch * 2048 + (size_t)mt * 128;
    const unsigned short* Hb = H + rowbase * 256;
    float* obase = out + rowbase * 256;
#pragma unroll
    for (int m = 0; m < 4; ++m) {
#pragma unroll
        for (int n = 0; n < 4; ++n) {
            int col = wc * 64 + n * 16 + lo;
#pragma unroll
            for (int j = 0; j < 4; ++j) {
                int row = wr * 64 + m * 16 + hi * 4 + j;
                float v = acc[m][n][j] + bf2f(Hb[(size_t)row * 256 + col]);
                obase[(size_t)row * 256 + col] = fmaxf(v, 0.f);
            }
        }
    }
}

// ---------------------------------------------------------------------------
extern "C" void kernel_launch(void* const* d_in, const int* in_sizes, int n_in,
                              void* d_out, int out_size, void* d_ws, size_t ws_size,
                              hipStream_t stream) {
    const float* features = (const float*)d_in[0];   // [16][2048][256]
    const float* A        = (const float*)d_in[1];   // [16][2048][2048]
    const float* weight   = (const float*)d_in[2];   // [512][256]
    const float* bias     = (const float*)d_in[3];   // [256]
    float* out = (float*)d_out;

    const size_t WT_B = (size_t)256 * 512 * 2;             // 256 KB
    const size_t H_B  = (size_t)32768 * 256 * 2;           // 16.78 MB
    const size_t GT_B = (size_t)16 * 256 * 2048 * 2;       // 16.78 MB
    if (ws_size < WT_B + H_B + GT_B) return;

    char* ws = (char*)d_ws;
    unsigned short* Wt = (unsigned short*)ws;
    unsigned short* H  = (unsigned short*)(ws + WT_B);
    unsigned short* Gt = (unsigned short*)(ws + WT_B + H_B);

    dim3 gW(512 / 64, 256 / 64, 1);
    transpose_cvt_kernel<<<gW, 256, 0, stream>>>(weight, Wt, nullptr, 512, 256);

    kpre_gemm<<<512, 256, 0, stream>>>(features, Wt, bias, H, Gt);

    kmain_gemm<<<256, 512, 0, stream>>>(A, Gt, H, out);
}